// Round 4
// baseline (330.153 us; speedup 1.0000x reference)
//
#include <hip/hip_runtime.h>

// ---------------------------------------------------------------------------
// CausalSelfAttention: B=2, T=2048, C=1024, H=16, HD=64
// Inputs fp32, output fp32; internal bf16 MFMA.
// ---------------------------------------------------------------------------

#define B_   2
#define T_   2048
#define C_   1024
#define H_   16
#define HD_  64
#define BT_  (B_ * T_)      // 4096
#define C3_  (3 * C_)       // 3072

typedef __attribute__((ext_vector_type(8))) __bf16 bf16x8;
typedef __attribute__((ext_vector_type(4))) float  f32x4;
typedef __attribute__((ext_vector_type(8))) unsigned short u16x8;

__device__ __forceinline__ unsigned short f2bf(float f) {
    unsigned int u = __float_as_uint(f);
    u = (u + 0x7fffu + ((u >> 16) & 1u)) >> 16;
    return (unsigned short)u;
}

#define GLOAD16(g, l) __builtin_amdgcn_global_load_lds(                          \
    (const __attribute__((address_space(1))) unsigned int*)(g),                  \
    (__attribute__((address_space(3))) unsigned int*)(l), 16, 0, 0)

// ---------------- fp32 -> bf16 convert (8 elems/thread) --------------------
__global__ __launch_bounds__(256) void cvt_bf16(const float* __restrict__ in,
                                                unsigned short* __restrict__ out,
                                                int n8) {
    int i = blockIdx.x * 256 + threadIdx.x;
    if (i >= n8) return;
    const float4* p = (const float4*)in;
    float4 f0 = p[i * 2];
    float4 f1 = p[i * 2 + 1];
    u16x8 o;
    o[0] = f2bf(f0.x); o[1] = f2bf(f0.y); o[2] = f2bf(f0.z); o[3] = f2bf(f0.w);
    o[4] = f2bf(f1.x); o[5] = f2bf(f1.y); o[6] = f2bf(f1.z); o[7] = f2bf(f1.w);
    ((u16x8*)out)[i] = o;
}

// ---------------- bf16 GEMM: C[M][N] = A[M][K] * B[N][K]^T + bias ----------
// m97 structure: 128x128 tile, BK=64, global_load_lds dwordx4, linear LDS.
template<int OUT_BF16>
__global__ __launch_bounds__(256) void gemm_lds(const unsigned short* __restrict__ A,
                                                const unsigned short* __restrict__ Bm,
                                                const float* __restrict__ bias,
                                                void* __restrict__ Cv,
                                                int M, int N, int K) {
    __shared__ __align__(16) unsigned short As[128][64];
    __shared__ __align__(16) unsigned short Bs[128][64];

    const int t    = threadIdx.x;
    const int lane = t & 63;
    const int w    = t >> 6;
    const int wr   = w & 1;
    const int wc   = w >> 1;
    const int l15  = lane & 15;
    const int lhi  = lane >> 4;
    const int m0   = blockIdx.y * 128;
    const int n0   = blockIdx.x * 128;
    const int lrow = lane >> 3;          // 0..7
    const int lcol = (lane & 7) * 8;     // 0,8,..,56

    f32x4 acc[4][4] = {};

    for (int kb = 0; kb < K; kb += 64) {
        __syncthreads();
        #pragma unroll
        for (int i = 0; i < 4; ++i) {
            int row = w * 32 + i * 8;
            GLOAD16(A  + (size_t)(m0 + row + lrow) * K + kb + lcol, &As[row][0]);
            GLOAD16(Bm + (size_t)(n0 + row + lrow) * K + kb + lcol, &Bs[row][0]);
        }
        __syncthreads();
        #pragma unroll
        for (int kk = 0; kk < 2; ++kk) {
            bf16x8 af[4], bfm[4];
            #pragma unroll
            for (int m = 0; m < 4; ++m)
                af[m] = *(const bf16x8*)(&As[wr * 64 + m * 16 + l15][kk * 32 + lhi * 8]);
            #pragma unroll
            for (int n = 0; n < 4; ++n)
                bfm[n] = *(const bf16x8*)(&Bs[wc * 64 + n * 16 + l15][kk * 32 + lhi * 8]);
            #pragma unroll
            for (int m = 0; m < 4; ++m)
                #pragma unroll
                for (int n = 0; n < 4; ++n)
                    acc[m][n] = __builtin_amdgcn_mfma_f32_16x16x32_bf16(af[m], bfm[n], acc[m][n], 0, 0, 0);
        }
    }

    #pragma unroll
    for (int n = 0; n < 4; ++n) {
        int cg = n0 + wc * 64 + n * 16 + l15;
        float bv = bias[cg];
        #pragma unroll
        for (int m = 0; m < 4; ++m) {
            #pragma unroll
            for (int i = 0; i < 4; ++i) {
                int rg  = m0 + wr * 64 + m * 16 + lhi * 4 + i;
                float v = acc[m][n][i] + bv;
                if (OUT_BF16)
                    ((unsigned short*)Cv)[(size_t)rg * N + cg] = f2bf(v);
                else
                    ((float*)Cv)[(size_t)rg * N + cg] = v;
            }
        }
    }
}

// ---------------- causal flash attention -----------------------------------
// grid = (T/64, B*H); 4 waves x 16 q-rows; KV tiles of 128.
// LDS: K tile (aliased by P after barrier [C]) + transposed V = 35.8 KB -> 4 blk/CU.
// T14 async-stage: next tile's K/V in regs during compute.
// NOTE: no min-waves launch bound — round 3's (256,4) clamped VGPR to 64 and
// spilled ~50 regs/thread -> 147 MB scratch writes per dispatch.
__global__ __launch_bounds__(256) void attn_fwd(const unsigned short* __restrict__ qkv,
                                                unsigned short* __restrict__ y) {
    __shared__ __align__(16) unsigned short KPs[128][72];   // K tile; P aliases it
    __shared__ __align__(16) unsigned short Vt[64][136];    // V transposed [d][key]

    const int t    = threadIdx.x;
    const int lane = t & 63;
    const int wv   = t >> 6;
    const int l15  = lane & 15;
    const int lhi  = lane >> 4;
    const int b    = blockIdx.y >> 4;
    const int h    = blockIdx.y & 15;
    const int qt   = gridDim.x - 1 - blockIdx.x;  // biggest tiles first
    const int q0   = qt * 64;
    const size_t rowbase = (size_t)b * T_ * C3_;
    const int hoff = h * HD_;
    unsigned short* PsW = &KPs[0][0] + wv * (16 * 136);  // wave-private P: 16x136

    bf16x8 qf[2];
    {
        int qrow = q0 + wv * 16 + l15;
        const unsigned short* qp = qkv + rowbase + (size_t)qrow * C3_ + hoff + lhi * 8;
        qf[0] = *(const bf16x8*)(qp);
        qf[1] = *(const bf16x8*)(qp + 32);
    }

    float Mx[4], Lx[4];
    f32x4 oacc[4];
    #pragma unroll
    for (int i = 0; i < 4; ++i) { Mx[i] = -1e30f; Lx[i] = 0.f; }
    #pragma unroll
    for (int n = 0; n < 4; ++n) oacc[n] = f32x4{0.f, 0.f, 0.f, 0.f};

    const unsigned short* kbase = qkv + rowbase + C_ + hoff;
    const unsigned short* vcol  = qkv + rowbase + 2 * C_ + hoff + lane;

    const int niter = (qt + 2) >> 1;

    uint4 kreg[4];
    u16x8 vreg[4];
    #pragma unroll
    for (int i = 0; i < 4; ++i) {
        int g = i * 256 + t;
        kreg[i] = *(const uint4*)(kbase + (size_t)(g >> 3) * C3_ + (g & 7) * 8);
    }
    #pragma unroll
    for (int pp = 0; pp < 4; ++pp) {
        int kb = pp * 32 + wv * 8;
        #pragma unroll
        for (int j = 0; j < 8; ++j)
            vreg[pp][j] = vcol[(size_t)(kb + j) * C3_];
    }

    for (int it = 0; it < niter; ++it) {
        const int k0 = it * 128;
        __syncthreads();                                   // [A] prev P/V reads done
        #pragma unroll
        for (int i = 0; i < 4; ++i) {
            int g = i * 256 + t;
            *(uint4*)(&KPs[g >> 3][(g & 7) * 8]) = kreg[i];
        }
        #pragma unroll
        for (int pp = 0; pp < 4; ++pp)
            *(u16x8*)(&Vt[lane][pp * 32 + wv * 8]) = vreg[pp];
        __syncthreads();                                   // [B] tile ready

        // issue next tile's global loads (latency hides under compute)
        if (it + 1 < niter) {
            const int kn = k0 + 128;
            #pragma unroll
            for (int i = 0; i < 4; ++i) {
                int g = i * 256 + t;
                kreg[i] = *(const uint4*)(kbase + (size_t)(kn + (g >> 3)) * C3_ + (g & 7) * 8);
            }
            #pragma unroll
            for (int pp = 0; pp < 4; ++pp) {
                int kb = kn + pp * 32 + wv * 8;
                #pragma unroll
                for (int j = 0; j < 8; ++j)
                    vreg[pp][j] = vcol[(size_t)(kb + j) * C3_];
            }
        }

        // S = Q K^T  (16 q-rows x 128 keys per wave)
        f32x4 sacc[8];
        #pragma unroll
        for (int n = 0; n < 8; ++n) sacc[n] = f32x4{0.f, 0.f, 0.f, 0.f};
        __builtin_amdgcn_s_setprio(1);
        #pragma unroll
        for (int kk = 0; kk < 2; ++kk) {
            #pragma unroll
            for (int n = 0; n < 8; ++n) {
                bf16x8 kf = *(const bf16x8*)(&KPs[n * 16 + l15][kk * 32 + lhi * 8]);
                sacc[n] = __builtin_amdgcn_mfma_f32_16x16x32_bf16(qf[kk], kf, sacc[n], 0, 0, 0);
            }
        }
        __builtin_amdgcn_s_setprio(0);
        __syncthreads();                                   // [C] K reads done -> P may overwrite

        if (k0 + 127 <= q0) {
            #pragma unroll
            for (int n = 0; n < 8; ++n)
                #pragma unroll
                for (int i = 0; i < 4; ++i)
                    sacc[n][i] *= 0.125f;
        } else {
            const int qgb = q0 + wv * 16 + lhi * 4;
            #pragma unroll
            for (int n = 0; n < 8; ++n) {
                int kg = k0 + n * 16 + l15;
                #pragma unroll
                for (int i = 0; i < 4; ++i)
                    sacc[n][i] = (kg <= qgb + i) ? sacc[n][i] * 0.125f : -1e30f;
            }
        }

        #pragma unroll
        for (int i = 0; i < 4; ++i) {
            float vm = sacc[0][i];
            #pragma unroll
            for (int n = 1; n < 8; ++n) vm = fmaxf(vm, sacc[n][i]);
            vm = fmaxf(vm, __shfl_xor(vm, 1));
            vm = fmaxf(vm, __shfl_xor(vm, 2));
            vm = fmaxf(vm, __shfl_xor(vm, 4));
            vm = fmaxf(vm, __shfl_xor(vm, 8));
            float Mn = fmaxf(Mx[i], vm);
            float al = __expf(Mx[i] - Mn);
            Mx[i] = Mn;
            float rs = 0.f;
            #pragma unroll
            for (int n = 0; n < 8; ++n) {
                float e = __expf(sacc[n][i] - Mn);
                sacc[n][i] = e;
                rs += e;
            }
            rs += __shfl_xor(rs, 1);
            rs += __shfl_xor(rs, 2);
            rs += __shfl_xor(rs, 4);
            rs += __shfl_xor(rs, 8);
            Lx[i] = Lx[i] * al + rs;
            #pragma unroll
            for (int n = 0; n < 4; ++n) oacc[n][i] *= al;
        }

        #pragma unroll
        for (int n = 0; n < 8; ++n)
            #pragma unroll
            for (int i = 0; i < 4; ++i)
                PsW[(lhi * 4 + i) * 136 + n * 16 + l15] = f2bf(sacc[n][i]);
        asm volatile("s_waitcnt lgkmcnt(0)" ::: "memory");

        __builtin_amdgcn_s_setprio(1);
        #pragma unroll
        for (int kk = 0; kk < 4; ++kk) {
            bf16x8 pf = *(const bf16x8*)(PsW + l15 * 136 + kk * 32 + lhi * 8);
            #pragma unroll
            for (int nd = 0; nd < 4; ++nd) {
                bf16x8 vf = *(const bf16x8*)(&Vt[nd * 16 + l15][kk * 32 + lhi * 8]);
                oacc[nd] = __builtin_amdgcn_mfma_f32_16x16x32_bf16(pf, vf, oacc[nd], 0, 0, 0);
            }
        }
        __builtin_amdgcn_s_setprio(0);
    }

    #pragma unroll
    for (int nd = 0; nd < 4; ++nd) {
        #pragma unroll
        for (int i = 0; i < 4; ++i) {
            int qg  = q0 + wv * 16 + lhi * 4 + i;
            float v = oacc[nd][i] / Lx[i];
            y[(size_t)(b * T_ + qg) * C_ + hoff + nd * 16 + l15] = f2bf(v);
        }
    }
}

// ---------------------------------------------------------------------------
extern "C" void kernel_launch(void* const* d_in, const int* in_sizes, int n_in,
                              void* d_out, int out_size, void* d_ws, size_t ws_size,
                              hipStream_t stream) {
    const float* x      = (const float*)d_in[0];
    const float* W_attn = (const float*)d_in[1];
    const float* b_attn = (const float*)d_in[2];
    const float* W_proj = (const float*)d_in[3];
    const float* b_proj = (const float*)d_in[4];
    float* out = (float*)d_out;

    char* ws = (char*)d_ws;
    unsigned short* xb   = (unsigned short*)(ws);                       // 4096x1024
    unsigned short* wab  = (unsigned short*)(ws + 8388608);             // 3072x1024
    unsigned short* wpb  = (unsigned short*)(ws + 8388608 + 6291456);   // 1024x1024
    unsigned short* qkvb = (unsigned short*)(ws + 16777216);            // 4096x3072
    unsigned short* yb   = (unsigned short*)(ws + 16777216 + 25165824); // 4096x1024

    cvt_bf16<<<(BT_ * C_ / 8 + 255) / 256, 256, 0, stream>>>(x, xb, BT_ * C_ / 8);
    cvt_bf16<<<(C3_ * C_ / 8 + 255) / 256, 256, 0, stream>>>(W_attn, wab, C3_ * C_ / 8);
    cvt_bf16<<<(C_ * C_ / 8 + 255) / 256, 256, 0, stream>>>(W_proj, wpb, C_ * C_ / 8);

    gemm_lds<1><<<dim3(C3_ / 128, BT_ / 128), 256, 0, stream>>>(xb, wab, b_attn, qkvb, BT_, C3_, C_);

    attn_fwd<<<dim3(T_ / 64, B_ * H_), 256, 0, stream>>>(qkvb, yb);

    gemm_lds<0><<<dim3(C_ / 128, BT_ / 128), 256, 0, stream>>>(yb, wpb, b_proj, out, BT_, C_, C_);
}

// Round 5
// 256.013 us; speedup vs baseline: 1.2896x; 1.2896x over previous
//
#include <hip/hip_runtime.h>

// ---------------------------------------------------------------------------
// CausalSelfAttention: B=2, T=2048, C=1024, H=16, HD=64
// Inputs fp32, output fp32; internal bf16 MFMA.
// R5 = R2 structure (known-good 119us attn) + swapped-QK in-lane softmax.
// ---------------------------------------------------------------------------

#define B_   2
#define T_   2048
#define C_   1024
#define H_   16
#define HD_  64
#define BT_  (B_ * T_)      // 4096
#define C3_  (3 * C_)       // 3072

typedef __attribute__((ext_vector_type(8))) __bf16 bf16x8;
typedef __attribute__((ext_vector_type(4))) float  f32x4;
typedef __attribute__((ext_vector_type(8))) unsigned short u16x8;

__device__ __forceinline__ unsigned short f2bf(float f) {
    unsigned int u = __float_as_uint(f);
    u = (u + 0x7fffu + ((u >> 16) & 1u)) >> 16;
    return (unsigned short)u;
}

// ---------------- fp32 -> bf16 convert (8 elems/thread) --------------------
__global__ __launch_bounds__(256) void cvt_bf16(const float* __restrict__ in,
                                                unsigned short* __restrict__ out,
                                                int n8) {
    int i = blockIdx.x * 256 + threadIdx.x;
    if (i >= n8) return;
    const float4* p = (const float4*)in;
    float4 f0 = p[i * 2];
    float4 f1 = p[i * 2 + 1];
    u16x8 o;
    o[0] = f2bf(f0.x); o[1] = f2bf(f0.y); o[2] = f2bf(f0.z); o[3] = f2bf(f0.w);
    o[4] = f2bf(f1.x); o[5] = f2bf(f1.y); o[6] = f2bf(f1.z); o[7] = f2bf(f1.w);
    ((u16x8*)out)[i] = o;
}

// ---------------- bf16 GEMM: C[M][N] = A[M][K] * B[N][K]^T + bias ----------
// R2 reg-staged version (known-good).
template<int OUT_BF16>
__global__ __launch_bounds__(256) void gemm_bt(const unsigned short* __restrict__ A,
                                               const unsigned short* __restrict__ Bm,
                                               const float* __restrict__ bias,
                                               void* __restrict__ Cv,
                                               int M, int N, int K) {
    __shared__ __align__(16) unsigned short As[128][72];
    __shared__ __align__(16) unsigned short Bs[128][72];

    const int t    = threadIdx.x;
    const int lane = t & 63;
    const int w    = t >> 6;
    const int wr   = w & 1;
    const int wc   = w >> 1;
    const int l15  = lane & 15;
    const int lhi  = lane >> 4;
    const int m0   = blockIdx.y * 128;
    const int n0   = blockIdx.x * 128;

    f32x4 acc[4][4] = {};

    const int nk = K >> 6;
    for (int kb = 0; kb < nk; ++kb) {
        __syncthreads();
        #pragma unroll
        for (int i = 0; i < 4; ++i) {
            int g   = i * 256 + t;
            int row = g >> 3;
            int kc  = g & 7;
            uint4 va = *(const uint4*)(A  + (size_t)(m0 + row) * K + kb * 64 + kc * 8);
            *(uint4*)(&As[row][kc * 8]) = va;
            uint4 vb = *(const uint4*)(Bm + (size_t)(n0 + row) * K + kb * 64 + kc * 8);
            *(uint4*)(&Bs[row][kc * 8]) = vb;
        }
        __syncthreads();
        #pragma unroll
        for (int kk = 0; kk < 2; ++kk) {
            bf16x8 af[4], bfm[4];
            #pragma unroll
            for (int m = 0; m < 4; ++m)
                af[m] = *(const bf16x8*)(&As[wr * 64 + m * 16 + l15][kk * 32 + lhi * 8]);
            #pragma unroll
            for (int n = 0; n < 4; ++n)
                bfm[n] = *(const bf16x8*)(&Bs[wc * 64 + n * 16 + l15][kk * 32 + lhi * 8]);
            #pragma unroll
            for (int m = 0; m < 4; ++m)
                #pragma unroll
                for (int n = 0; n < 4; ++n)
                    acc[m][n] = __builtin_amdgcn_mfma_f32_16x16x32_bf16(af[m], bfm[n], acc[m][n], 0, 0, 0);
        }
    }

    #pragma unroll
    for (int n = 0; n < 4; ++n) {
        int cg = n0 + wc * 64 + n * 16 + l15;
        float bv = bias[cg];
        #pragma unroll
        for (int m = 0; m < 4; ++m) {
            #pragma unroll
            for (int i = 0; i < 4; ++i) {
                int rg  = m0 + wr * 64 + m * 16 + lhi * 4 + i;
                float v = acc[m][n][i] + bv;
                if (OUT_BF16)
                    ((unsigned short*)Cv)[(size_t)rg * N + cg] = f2bf(v);
                else
                    ((float*)Cv)[(size_t)rg * N + cg] = v;
            }
        }
    }
}

// ---------------- causal flash attention -----------------------------------
// grid = (T/64, B*H); block = 256 (4 waves x 16 q-rows). KV tiles of 128.
// Swapped QK^T: sacc[n][r] = S[key=k0+n*16+lhi*4+r][q=q0+wv*16+l15]
//   -> each lane owns one q-row; softmax is in-lane + 2 shfl_xor rounds.
// exp2-domain softmax: scale = 0.125*log2(e); exp2f maps to raw v_exp_f32.
__global__ __launch_bounds__(256) void attn_fwd(const unsigned short* __restrict__ qkv,
                                                unsigned short* __restrict__ y) {
    __shared__ __align__(16) unsigned short Ks[128][72];
    __shared__ __align__(16) unsigned short Vt[64][136];   // V transposed [d][key]
    __shared__ __align__(16) unsigned short Ps[4][16][136];

    const int t    = threadIdx.x;
    const int lane = t & 63;
    const int wv   = t >> 6;
    const int l15  = lane & 15;
    const int lhi  = lane >> 4;
    const int b    = blockIdx.y >> 4;
    const int h    = blockIdx.y & 15;
    const int qt   = gridDim.x - 1 - blockIdx.x;  // biggest tiles first
    const int q0   = qt * 64;
    const size_t rowbase = (size_t)b * T_ * C3_;
    const int hoff = h * HD_;

    // Q fragments in registers for the whole kernel (B-operand of swapped QK)
    bf16x8 qf[2];
    {
        int qrow = q0 + wv * 16 + l15;
        const unsigned short* qp = qkv + rowbase + (size_t)qrow * C3_ + hoff + lhi * 8;
        qf[0] = *(const bf16x8*)(qp);
        qf[1] = *(const bf16x8*)(qp + 32);
    }

    float Mx = -1e30f, Lx = 0.f;     // per-lane: q-row = q0 + wv*16 + l15
    f32x4 oacc[4];
    #pragma unroll
    for (int n = 0; n < 4; ++n) oacc[n] = f32x4{0.f, 0.f, 0.f, 0.f};

    const int vd = t & 63;
    const int vk = t >> 6;
    const unsigned short* vcol = qkv + rowbase + 2 * C_ + hoff + vd;
    const unsigned short* krow = qkv + rowbase + C_ + hoff;

    const float SCL = 0.18033688f;   // 0.125 * log2(e)

    const int niter = (qt + 2) >> 1;
    for (int it = 0; it < niter; ++it) {
        const int k0 = it * 128;
        __syncthreads();
        // K tile: coalesced b128
        #pragma unroll
        for (int i = 0; i < 4; ++i) {
            int g   = i * 256 + t;
            int row = g >> 3;
            int kc  = g & 7;
            *(uint4*)(&Ks[row][kc * 8]) =
                *(const uint4*)(krow + (size_t)(k0 + row) * C3_ + kc * 8);
        }
        // V tile transposed via transposed global reads + b128 LDS writes
        #pragma unroll
        for (int pp = 0; pp < 4; ++pp) {
            int kb = pp * 32 + vk * 8;
            u16x8 vv;
            #pragma unroll
            for (int j = 0; j < 8; ++j)
                vv[j] = vcol[(size_t)(k0 + kb + j) * C3_];
            *(u16x8*)(&Vt[vd][kb]) = vv;
        }
        __syncthreads();

        // S^T = K Q^T  (swapped: col=q-row, row=key)
        f32x4 sacc[8];
        #pragma unroll
        for (int n = 0; n < 8; ++n) sacc[n] = f32x4{0.f, 0.f, 0.f, 0.f};
        __builtin_amdgcn_s_setprio(1);
        #pragma unroll
        for (int kk = 0; kk < 2; ++kk) {
            #pragma unroll
            for (int n = 0; n < 8; ++n) {
                bf16x8 kf = *(const bf16x8*)(&Ks[n * 16 + l15][kk * 32 + lhi * 8]);
                sacc[n] = __builtin_amdgcn_mfma_f32_16x16x32_bf16(kf, qf[kk], sacc[n], 0, 0, 0);
            }
        }
        __builtin_amdgcn_s_setprio(0);

        // scale (log2 domain) + causal mask; lane's q-row is fixed
        const int qg = q0 + wv * 16 + l15;
        if (k0 + 127 <= q0) {
            #pragma unroll
            for (int n = 0; n < 8; ++n)
                #pragma unroll
                for (int r = 0; r < 4; ++r)
                    sacc[n][r] *= SCL;
        } else {
            #pragma unroll
            for (int n = 0; n < 8; ++n) {
                int kg = k0 + n * 16 + lhi * 4;
                #pragma unroll
                for (int r = 0; r < 4; ++r)
                    sacc[n][r] = (kg + r <= qg) ? sacc[n][r] * SCL : -1e30f;
            }
        }

        // in-lane softmax over 32 values + 2-round cross-group reduce
        float vm = sacc[0][0];
        #pragma unroll
        for (int n = 0; n < 8; ++n)
            #pragma unroll
            for (int r = 0; r < 4; ++r) vm = fmaxf(vm, sacc[n][r]);
        vm = fmaxf(vm, __shfl_xor(vm, 16));
        vm = fmaxf(vm, __shfl_xor(vm, 32));
        float Mn = fmaxf(Mx, vm);
        float al = exp2f(Mx - Mn);
        Mx = Mn;
        float rs = 0.f;
        #pragma unroll
        for (int n = 0; n < 8; ++n)
            #pragma unroll
            for (int r = 0; r < 4; ++r) {
                float e = exp2f(sacc[n][r] - Mn);
                sacc[n][r] = e;
                rs += e;
            }
        rs += __shfl_xor(rs, 16);
        rs += __shfl_xor(rs, 32);
        Lx = Lx * al + rs;

        // rescale O: oacc rows are q = lhi*4 + r -> broadcast alpha from lane q
        #pragma unroll
        for (int r = 0; r < 4; ++r) {
            float ar = __shfl(al, lhi * 4 + r);
            #pragma unroll
            for (int nd = 0; nd < 4; ++nd) oacc[nd][r] *= ar;
        }

        // P -> LDS: lane's 4 consecutive keys per n -> one b64 packed write
        #pragma unroll
        for (int n = 0; n < 8; ++n) {
            unsigned int lo = (unsigned int)f2bf(sacc[n][0]) | ((unsigned int)f2bf(sacc[n][1]) << 16);
            unsigned int hi = (unsigned int)f2bf(sacc[n][2]) | ((unsigned int)f2bf(sacc[n][3]) << 16);
            uint2 pk; pk.x = lo; pk.y = hi;
            *(uint2*)(&Ps[wv][l15][n * 16 + lhi * 4]) = pk;
        }
        asm volatile("s_waitcnt lgkmcnt(0)" ::: "memory");

        __builtin_amdgcn_s_setprio(1);
        #pragma unroll
        for (int kk = 0; kk < 4; ++kk) {
            bf16x8 pf = *(const bf16x8*)(&Ps[wv][l15][kk * 32 + lhi * 8]);
            #pragma unroll
            for (int nd = 0; nd < 4; ++nd) {
                bf16x8 vf = *(const bf16x8*)(&Vt[nd * 16 + l15][kk * 32 + lhi * 8]);
                oacc[nd] = __builtin_amdgcn_mfma_f32_16x16x32_bf16(pf, vf, oacc[nd], 0, 0, 0);
            }
        }
        __builtin_amdgcn_s_setprio(0);
    }

    // epilogue: O / L -> y; oacc rows are q = lhi*4+i, L lives at lane q
    #pragma unroll
    for (int i = 0; i < 4; ++i) {
        float Lr = __shfl(Lx, lhi * 4 + i);
        float rL = 1.0f / Lr;
        #pragma unroll
        for (int nd = 0; nd < 4; ++nd) {
            int qg = q0 + wv * 16 + lhi * 4 + i;
            y[(size_t)(b * T_ + qg) * C_ + hoff + nd * 16 + l15] = f2bf(oacc[nd][i] * rL);
        }
    }
}

// ---------------------------------------------------------------------------
extern "C" void kernel_launch(void* const* d_in, const int* in_sizes, int n_in,
                              void* d_out, int out_size, void* d_ws, size_t ws_size,
                              hipStream_t stream) {
    const float* x      = (const float*)d_in[0];
    const float* W_attn = (const float*)d_in[1];
    const float* b_attn = (const float*)d_in[2];
    const float* W_proj = (const float*)d_in[3];
    const float* b_proj = (const float*)d_in[4];
    float* out = (float*)d_out;

    char* ws = (char*)d_ws;
    unsigned short* xb   = (unsigned short*)(ws);                       // 4096x1024
    unsigned short* wab  = (unsigned short*)(ws + 8388608);             // 3072x1024
    unsigned short* wpb  = (unsigned short*)(ws + 8388608 + 6291456);   // 1024x1024
    unsigned short* qkvb = (unsigned short*)(ws + 16777216);            // 4096x3072
    unsigned short* yb   = (unsigned short*)(ws + 16777216 + 25165824); // 4096x1024

    cvt_bf16<<<(BT_ * C_ / 8 + 255) / 256, 256, 0, stream>>>(x, xb, BT_ * C_ / 8);
    cvt_bf16<<<(C3_ * C_ / 8 + 255) / 256, 256, 0, stream>>>(W_attn, wab, C3_ * C_ / 8);
    cvt_bf16<<<(C_ * C_ / 8 + 255) / 256, 256, 0, stream>>>(W_proj, wpb, C_ * C_ / 8);

    gemm_bt<1><<<dim3(C3_ / 128, BT_ / 128), 256, 0, stream>>>(xb, wab, b_attn, qkvb, BT_, C3_, C_);

    attn_fwd<<<dim3(T_ / 64, B_ * H_), 256, 0, stream>>>(qkvb, yb);

    gemm_bt<0><<<dim3(C_ / 128, BT_ / 128), 256, 0, stream>>>(yb, wpb, b_proj, out, BT_, C_, C_);
}